// Round 5
// baseline (357.194 us; speedup 1.0000x reference)
//
#include <hip/hip_runtime.h>
#include <math.h>

#define BATCH 32768
#define SPW 4              // samples per wave/block
#define NBLK (BATCH / SPW)
#define NE 9
#define RANK 50
#define DIM 450            // NE * RANK
#define REL_DIM 900        // 2 * DIM
#define N_REL 22
#define EPSV 2.2204460492503131e-16f

__device__ __forceinline__ float softplusf(float x) {
    return (x > 20.f) ? x : log1pf(expf(x));
}
__device__ __forceinline__ float phif(float z) {
    return 0.5f * (1.f + erff(z * 0.70710678118654752f));
}

// Per-relation precompute: pure-rel conv outputs' dot contributions (o in [48,128)),
// Givens cos/sin table, softplus(c); zero global sums + counter. 22 blocks.
__global__ __launch_bounds__(64) void k_pre(
    const float* __restrict__ rel, const float* __restrict__ rel_diag,
    const float* __restrict__ c_param,
    const float* __restrict__ cnn_w, const float* __restrict__ cnn_b,
    const float* __restrict__ cnnn_w, const float* __restrict__ cnnn_b,
    const float* __restrict__ h2e_w, const float* __restrict__ h2en_w,
    float* __restrict__ cs_tab, float* __restrict__ pre_out, float* __restrict__ c_soft,
    float* __restrict__ gsums, int* __restrict__ counter)
{
    const int r = blockIdx.x;
    const int l = threadIdx.x;
    __shared__ float rl[REL_DIM];
    __shared__ float fA[80], fB[80];

    const float* relp = rel + (size_t)r * REL_DIM;
    for (int i = l; i < REL_DIM; i += 64) rl[i] = relp[i];
    __syncthreads();

    const float cb0 = cnn_b[0], cb1 = cnnn_b[0];
    for (int idx = l; idx < 80; idx += 64) {
        int o = 48 + idx;
        int oh = o >> 4, ow = o & 15;
        const float* base = rl + (oh * 3 - 9) * RANK + ow * 3;   // rel image rows
        float a0 = cb0, a1 = cb1;
#pragma unroll
        for (int i = 0; i < 5; ++i)
#pragma unroll
            for (int j = 0; j < 5; ++j) {
                float v = base[i * RANK + j];
                a0 = fmaf(v, cnn_w[i * 5 + j], a0);
                a1 = fmaf(v, cnnn_w[i * 5 + j], a1);
            }
        fA[idx] = a0; fB[idx] = a1;
    }
    __syncthreads();

    if (l < 18) {
        int e = (l < 9) ? l : (l - 9);
        const float* w = ((l < 9) ? (h2e_w + e * 128) : (h2en_w + e * 128)) + 48;
        const float* f = (l < 9) ? fA : fB;
        float acc = 0.f;
#pragma unroll 8
        for (int t = 0; t < 80; ++t) acc = fmaf(f[t], w[t], acc);
        pre_out[r * 18 + l] = acc;
    }
    if (l == 63) c_soft[r] = softplusf(c_param[r]);
    if (r == 0) {
        if (l >= 32 && l < 50) gsums[l - 32] = 0.f;   // zero 18 accumulators
        if (l == 62) *counter = 0;
    }

    const float2* rd2 = (const float2*)(rel_diag + (size_t)r * DIM);
    float2* cs2 = (float2*)(cs_tab + (size_t)r * DIM);
    for (int u = l; u < 225; u += 64) {
        float2 v = rd2[u];
        float nrm = fmaxf(sqrtf(v.x * v.x + v.y * v.y), 1e-15f);
        cs2[u] = make_float2(v.x / nrm, v.y / nrm);
    }
}

struct WaveShm {
    float  xs[552];          // image rows 0..10: head(450) ++ rel[0:100]
    float2 fs[51];           // (feat, featn) per o<48, padded 1/16
    float  clean[NE], stdv[NE], noisy[NE];
    float  sg[2], sthr[2];   // sthr[0]=thr_in (3rd), [1]=thr_out (2nd)
    int    sidx[2];
};

// One 64-lane wave per workgroup; each wave processes SPW samples sequentially.
__global__ __launch_bounds__(64) void k_main(
    const int* __restrict__ queries, const int* __restrict__ these_queries,
    const float* __restrict__ entity, const float* __restrict__ rel,
    const float* __restrict__ bh, const float* __restrict__ bt,
    const float* __restrict__ cnn_w, const float* __restrict__ cnn_b,
    const float* __restrict__ h2e_w, const float* __restrict__ h2e_b,
    const float* __restrict__ cnnn_w, const float* __restrict__ cnnn_b,
    const float* __restrict__ h2en_w, const float* __restrict__ h2en_b,
    const float* __restrict__ noise,
    const float* __restrict__ cs_tab, const float* __restrict__ pre_out,
    const float* __restrict__ c_soft,
    float* __restrict__ y_out, float* __restrict__ gsums, int* __restrict__ counter)
{
    __shared__ WaveShm S;
    const int l = threadIdx.x;
    float2* xs2 = (float2*)S.xs;

    // ---- block-invariant: cache the 16 dot-weights for this lane in VGPRs ----
    const int chunk = l / 18, j18 = l - chunk * 18;
    float wreg[16];
    if (l < 54) {
        int e = (j18 < 9) ? j18 : (j18 - 9);
        const float* wrow = ((j18 < 9) ? (h2e_w + e * 128) : (h2en_w + e * 128)) + chunk * 16;
#pragma unroll
        for (int k = 0; k < 16; ++k) wreg[k] = wrow[k];
    } else {
#pragma unroll
        for (int k = 0; k < 16; ++k) wreg[k] = 0.f;
    }
    const float cb0 = cnn_b[0], cb1 = cnnn_b[0];
    float bias18 = 0.f;
    if (l < 9)            bias18 = h2e_b[l];
    else if (l < 18)      bias18 = h2en_b[l - 9];

    float accum = 0.f;   // lanes 0-8: sum of gates; lanes 9-17: sum of probs

    for (int s = 0; s < SPW; ++s) {
        const int b = blockIdx.x * SPW + s;

        const int q0 = queries[b * 3 + 0];
        const int q1 = queries[b * 3 + 1];
        const int t2 = these_queries[b * 3 + 2];

        const float2* hp2 = (const float2*)(entity + (size_t)q0 * DIM);   // 225 float2
        const float2* rp2 = (const float2*)(rel + (size_t)q1 * REL_DIM);  // first 50

        // ---- staging loads ----
        float2 h2[4];
#pragma unroll
        for (int k = 0; k < 4; ++k) { int i = l + 64 * k; if (i < 225) h2[k] = hp2[i]; }
        float2 rr2 = make_float2(0.f, 0.f);
        if (l < 50) rr2 = rp2[l];
        float nz = 0.f;
        if (l < NE) nz = noise[(size_t)b * NE + l];
        float pre_v = 0.f;
        if (l < 18) pre_v = pre_out[q1 * 18 + l];

        __syncthreads();   // WAR: prior sample's xs readers done (single-wave: waitcnt only)
#pragma unroll
        for (int k = 0; k < 4; ++k) { int i = l + 64 * k; if (i < 225) xs2[i] = h2[k]; }
        if (l < 50) xs2[225 + l] = rr2;
        __syncthreads();

        // ---- conv: sample-dependent outputs o < 48 (oh 0..2), both kernels ----
        if (l < 48) {
            int oh = l >> 4, ow = l & 15;
            const float* base = S.xs + (oh * 3) * RANK + ow * 3;
            float a0 = cb0, a1 = cb1;
#pragma unroll
            for (int i = 0; i < 5; ++i)
#pragma unroll
                for (int j = 0; j < 5; ++j) {
                    float v = base[i * RANK + j];
                    a0 = fmaf(v, cnn_w[i * 5 + j], a0);
                    a1 = fmaf(v, cnnn_w[i * 5 + j], a1);
                }
            S.fs[l + (l >> 4)] = make_float2(a0, a1);
        }
        __syncthreads();

        // ---- 18 dots of length 48: 54 lanes, 16 terms each (weights in regs) ----
        float acc = 0.f;
        if (l < 54) {
            int fbase = chunk * 17;   // padded chunk base
            if (j18 < 9) {
#pragma unroll
                for (int k = 0; k < 16; ++k) acc = fmaf(S.fs[fbase + k].x, wreg[k], acc);
            } else {
#pragma unroll
                for (int k = 0; k < 16; ++k) acc = fmaf(S.fs[fbase + k].y, wreg[k], acc);
            }
        }
        float pA = __shfl_down(acc, 18);
        float pB = __shfl_down(acc, 36);
        float tot = acc + pA + pB;                  // valid for l < 18
        if (l < 9)        S.clean[l]     = tot + pre_v + bias18;
        else if (l < 18)  S.stdv[l - 9]  = softplusf(tot + pre_v + bias18) + 0.01f;
        __syncthreads();
        if (l < NE) S.noisy[l] = fmaf(nz, S.stdv[l], S.clean[l]);
        __syncthreads();

        // ---- top-3 of 9 (ties -> lower index, matching lax.top_k) ----
        if (l == 0) {
            int i0 = -1, i1 = -1;
            float v0 = -__builtin_huge_valf(), v1 = v0, v2 = v0;
#pragma unroll
            for (int e = 0; e < NE; ++e) {
                float v = S.noisy[e];
                if (v > v0)      { v2 = v1; v1 = v0; i1 = i0; v0 = v; i0 = e; }
                else if (v > v1) { v2 = v1; v1 = v; i1 = e; }
                else if (v > v2) { v2 = v; }
            }
            float e1 = expf(v1 - v0);
            float inv = 1.f / (1.f + e1);
            S.sidx[0] = i0; S.sidx[1] = i1;
            S.sg[0] = inv; S.sg[1] = e1 * inv;
            S.sthr[0] = v2; S.sthr[1] = v1;
        }
        __syncthreads();

        // ---- Givens + dist2 for the 2 selected experts; lanes 0-24 & 32-56 ----
        float contrib = 0.f;
        bool act = (l < 25) || (l >= 32 && l < 57);
        if (act) {
            int sel = (l >= 32) ? 1 : 0;
            int p = l - 32 * sel;
            int e = S.sidx[sel];
            int u = e * 25 + p;
            float2 cs = *(const float2*)(cs_tab + (size_t)q1 * DIM + 2 * u);
            float2 rl = *(const float2*)(rel + (size_t)q1 * REL_DIM + e * 100 + 2 * p);
            float2 rh = *(const float2*)(entity + (size_t)t2 * DIM + 2 * u);
            float2 x  = xs2[u];
            float o0 = cs.x * x.x - cs.y * x.y + rl.x;
            float o1 = cs.y * x.x + cs.x * x.y + rl.y;
            float d0 = o0 - rh.x, d1 = o1 - rh.y;
            contrib = fmaf(d0, d0, d1 * d1);
        }

        // ---- accumulate gates/probs in registers while Givens loads are in flight ----
        if (l < NE) {
            float g = (l == S.sidx[0]) ? S.sg[0] : ((l == S.sidx[1]) ? S.sg[1] : 0.f);
            accum += g;
        } else if (l < 18) {
            int e = l - 9;
            float thr_in = S.sthr[0], thr_out = S.sthr[1];
            float n = S.noisy[e];
            float thr = (n > thr_in) ? thr_in : thr_out;
            accum += phif((S.clean[e] - thr) / S.stdv[e]);
        }

        // reduce contrib within each 32-lane half (xor stays inside the half)
#pragma unroll
        for (int off = 16; off; off >>= 1) contrib += __shfl_xor(contrib, off);
        float d2b = __shfl(contrib, 32);
        if (l == 0) {
            float c = c_soft[q1];
            float base = bh[q0] + bt[t2];
            float sum = expf(base - c * contrib) + expf(base - c * d2b);
            y_out[b] = logf((sum == 0.f) ? EPSV : sum);
        }
    }

    // ---- one atomic per lane (<18) per block into the global 18 sums ----
    if (l < 18) atomicAdd(&gsums[l], accum);

    // ---- last-block-done: compute cv^2 loss ----
    __shared__ int is_last;
    __threadfence();
    if (l == 0) is_last = (atomicAdd(counter, 1) == NBLK - 1) ? 1 : 0;
    __syncthreads();
    if (!is_last) return;
    __threadfence();

    if (l == 0) {
        volatile float* vs = (volatile float*)gsums;
        float loss = 0.f;
#pragma unroll
        for (int part = 0; part < 2; ++part) {
            float v[NE];
            for (int i = 0; i < NE; ++i) v[i] = vs[part * NE + i];
            float mean = 0.f;
            for (int i = 0; i < NE; ++i) mean += v[i];
            mean /= 9.f;
            float var = 0.f;
            for (int i = 0; i < NE; ++i) { float d = v[i] - mean; var += d * d; }
            var /= 8.f;                   // ddof=1
            loss += var / (mean * mean + 1e-10f);
        }
        y_out[BATCH] = 0.01f * loss;
    }
}

extern "C" void kernel_launch(void* const* d_in, const int* in_sizes, int n_in,
                              void* d_out, int out_size, void* d_ws, size_t ws_size,
                              hipStream_t stream)
{
    const int*   queries = (const int*)d_in[0];
    const int*   these   = (const int*)d_in[1];
    const float* entity  = (const float*)d_in[2];
    const float* rel     = (const float*)d_in[3];
    const float* rel_dg  = (const float*)d_in[4];
    const float* bh      = (const float*)d_in[5];
    const float* bt      = (const float*)d_in[6];
    const float* c_par   = (const float*)d_in[7];
    const float* cnn_w   = (const float*)d_in[8];
    const float* cnn_b   = (const float*)d_in[9];
    const float* h2e_w   = (const float*)d_in[10];
    const float* h2e_b   = (const float*)d_in[11];
    const float* cnnn_w  = (const float*)d_in[12];
    const float* cnnn_b  = (const float*)d_in[13];
    const float* h2en_w  = (const float*)d_in[14];
    const float* h2en_b  = (const float*)d_in[15];
    const float* noise   = (const float*)d_in[16];

    float* y  = (float*)d_out;
    float* ws = (float*)d_ws;
    float* cs_tab  = ws;                                      // 22*450
    float* pre_out = cs_tab + N_REL * DIM;                    // 22*18
    float* c_soft  = pre_out + N_REL * 18;                    // 22
    float* gsums   = c_soft + N_REL;                          // 18
    int*   counter = (int*)(gsums + 18);                      // 1

    k_pre<<<N_REL, 64, 0, stream>>>(rel, rel_dg, c_par, cnn_w, cnn_b, cnnn_w, cnnn_b,
                                    h2e_w, h2en_w, cs_tab, pre_out, c_soft, gsums, counter);
    k_main<<<NBLK, 64, 0, stream>>>(queries, these, entity, rel, bh, bt,
                                    cnn_w, cnn_b, h2e_w, h2e_b, cnnn_w, cnnn_b,
                                    h2en_w, h2en_b, noise, cs_tab, pre_out, c_soft,
                                    y, gsums, counter);
}

// Round 6
// 196.188 us; speedup vs baseline: 1.8207x; 1.8207x over previous
//
#include <hip/hip_runtime.h>
#include <math.h>

#define BATCH 32768
#define NE 9
#define RANK 50
#define DIM 450            // NE * RANK
#define REL_DIM 900        // 2 * DIM
#define N_REL 22
#define EPSV 2.2204460492503131e-16f

__device__ __forceinline__ float softplusf(float x) {
    return (x > 20.f) ? x : log1pf(expf(x));
}
__device__ __forceinline__ float phif(float z) {
    return 0.5f * (1.f + erff(z * 0.70710678118654752f));
}

// Per-relation precompute: pure-rel conv outputs' dot contributions (o in [48,128)),
// Givens cos/sin table, softplus(c), zero the reduce counter. 22 blocks.
__global__ __launch_bounds__(64) void k_pre(
    const float* __restrict__ rel, const float* __restrict__ rel_diag,
    const float* __restrict__ c_param,
    const float* __restrict__ cnn_w, const float* __restrict__ cnn_b,
    const float* __restrict__ cnnn_w, const float* __restrict__ cnnn_b,
    const float* __restrict__ h2e_w, const float* __restrict__ h2en_w,
    float* __restrict__ cs_tab, float* __restrict__ pre_out, float* __restrict__ c_soft,
    int* __restrict__ counter)
{
    const int r = blockIdx.x;
    const int l = threadIdx.x;
    __shared__ float rl[REL_DIM];
    __shared__ float fA[80], fB[80];

    const float* relp = rel + (size_t)r * REL_DIM;
    for (int i = l; i < REL_DIM; i += 64) rl[i] = relp[i];
    __syncthreads();

    const float cb0 = cnn_b[0], cb1 = cnnn_b[0];
    for (int idx = l; idx < 80; idx += 64) {
        int o = 48 + idx;
        int oh = o >> 4, ow = o & 15;
        const float* base = rl + (oh * 3 - 9) * RANK + ow * 3;   // rel image rows
        float a0 = cb0, a1 = cb1;
#pragma unroll
        for (int i = 0; i < 5; ++i)
#pragma unroll
            for (int j = 0; j < 5; ++j) {
                float v = base[i * RANK + j];
                a0 = fmaf(v, cnn_w[i * 5 + j], a0);
                a1 = fmaf(v, cnnn_w[i * 5 + j], a1);
            }
        fA[idx] = a0; fB[idx] = a1;
    }
    __syncthreads();

    if (l < 18) {
        int e = (l < 9) ? l : (l - 9);
        const float* w = ((l < 9) ? (h2e_w + e * 128) : (h2en_w + e * 128)) + 48;
        const float* f = (l < 9) ? fA : fB;
        float acc = 0.f;
#pragma unroll 8
        for (int t = 0; t < 80; ++t) acc = fmaf(f[t], w[t], acc);
        pre_out[r * 18 + l] = acc;
    }
    if (l == 63) c_soft[r] = softplusf(c_param[r]);
    if (r == 0 && l == 62) *counter = 0;        // zero last-block counter each launch

    const float2* rd2 = (const float2*)(rel_diag + (size_t)r * DIM);
    float2* cs2 = (float2*)(cs_tab + (size_t)r * DIM);
    for (int u = l; u < 225; u += 64) {
        float2 v = rd2[u];
        float nrm = fmaxf(sqrtf(v.x * v.x + v.y * v.y), 1e-15f);
        cs2[u] = make_float2(v.x / nrm, v.y / nrm);
    }
}

// One 64-lane wave per sample. (R3 structure — proven fastest.)
__global__ __launch_bounds__(64) void k_main(
    const int* __restrict__ queries, const int* __restrict__ these_queries,
    const float* __restrict__ entity, const float* __restrict__ rel,
    const float* __restrict__ bh, const float* __restrict__ bt,
    const float* __restrict__ cnn_w, const float* __restrict__ cnn_b,
    const float* __restrict__ h2e_w, const float* __restrict__ h2e_b,
    const float* __restrict__ cnnn_w, const float* __restrict__ cnnn_b,
    const float* __restrict__ h2en_w, const float* __restrict__ h2en_b,
    const float* __restrict__ noise,
    const float* __restrict__ cs_tab, const float* __restrict__ pre_out,
    const float* __restrict__ c_soft,
    float* __restrict__ y_out, float* __restrict__ ws_rows)
{
    const int b = blockIdx.x;
    const int l = threadIdx.x;

    __shared__ __align__(16) float xs[552];     // image rows 0..10: head(450) ++ rel[0:100]
    __shared__ __align__(16) float2 fs[51];     // (feat, featn) per o<48, padded 1/16
    __shared__ float clean_s[NE], stdv_s[NE], noisy_s[NE];
    __shared__ int   sidx[2];
    __shared__ float sg[2];
    __shared__ float sthr[2];                   // [0]=thr_in (3rd), [1]=thr_out (2nd)

    const int q0 = queries[b * 3 + 0];
    const int q1 = queries[b * 3 + 1];
    const int t2 = these_queries[b * 3 + 2];

    const float2* hp2 = (const float2*)(entity + (size_t)q0 * DIM);   // 225 float2
    const float2* rp2 = (const float2*)(rel + (size_t)q1 * REL_DIM);  // first 50

    // ---- issue staging loads early ----
    float2 h2[4];
#pragma unroll
    for (int k = 0; k < 4; ++k) { int i = l + 64 * k; if (i < 225) h2[k] = hp2[i]; }
    float2 rr2 = make_float2(0.f, 0.f);
    if (l < 50) rr2 = rp2[l];
    float nz = 0.f;
    if (l < NE) nz = noise[(size_t)b * NE + l];
    float pre_v = 0.f;
    if (l < 18) pre_v = pre_out[q1 * 18 + l];

    float2* xs2 = (float2*)xs;
#pragma unroll
    for (int k = 0; k < 4; ++k) { int i = l + 64 * k; if (i < 225) xs2[i] = h2[k]; }
    if (l < 50) xs2[225 + l] = rr2;
    __syncthreads();

    // ---- conv: sample-dependent outputs o < 48 (oh 0..2), both kernels ----
    if (l < 48) {
        int oh = l >> 4, ow = l & 15;
        const float* base = xs + (oh * 3) * RANK + ow * 3;
        float a0 = cnn_b[0], a1 = cnnn_b[0];
#pragma unroll
        for (int i = 0; i < 5; ++i)
#pragma unroll
            for (int j = 0; j < 5; ++j) {
                float v = base[i * RANK + j];
                a0 = fmaf(v, cnn_w[i * 5 + j], a0);
                a1 = fmaf(v, cnnn_w[i * 5 + j], a1);
            }
        fs[l + (l >> 4)] = make_float2(a0, a1);
    }
    __syncthreads();

    // ---- 18 dots of length 48: 54 lanes, 16 terms each ----
    float acc = 0.f;
    if (l < 54) {
        int chunk = l / 18, j = l - chunk * 18;
        int e = (j < 9) ? j : (j - 9);
        const float* wrow = ((j < 9) ? (h2e_w + e * 128) : (h2en_w + e * 128)) + chunk * 16;
        int fbase = chunk * 17;   // padded chunk base
        if (j < 9) {
#pragma unroll
            for (int k = 0; k < 16; ++k) acc = fmaf(fs[fbase + k].x, wrow[k], acc);
        } else {
#pragma unroll
            for (int k = 0; k < 16; ++k) acc = fmaf(fs[fbase + k].y, wrow[k], acc);
        }
    }
    float pA = __shfl_down(acc, 18);
    float pB = __shfl_down(acc, 36);
    float tot = acc + pA + pB;                  // valid for l < 18
    if (l < 9)        clean_s[l]     = tot + pre_v + h2e_b[l];
    else if (l < 18)  stdv_s[l - 9]  = softplusf(tot + pre_v + h2en_b[l - 9]) + 0.01f;
    __syncthreads();
    if (l < NE) noisy_s[l] = fmaf(nz, stdv_s[l], clean_s[l]);
    __syncthreads();

    // ---- top-3 of 9 (ties -> lower index, matching lax.top_k) ----
    if (l == 0) {
        int i0 = -1, i1 = -1;
        float v0 = -__builtin_huge_valf(), v1 = v0, v2 = v0;
#pragma unroll
        for (int e = 0; e < NE; ++e) {
            float v = noisy_s[e];
            if (v > v0)      { v2 = v1; v1 = v0; i1 = i0; v0 = v; i0 = e; }
            else if (v > v1) { v2 = v1; v1 = v; i1 = e; }
            else if (v > v2) { v2 = v; }
        }
        float e1 = expf(v1 - v0);
        float inv = 1.f / (1.f + e1);
        sidx[0] = i0; sidx[1] = i1;
        sg[0] = inv; sg[1] = e1 * inv;
        sthr[0] = v2; sthr[1] = v1;
    }
    __syncthreads();

    // ---- Givens + dist2 for the 2 selected experts; lanes 0-24 & 32-56 ----
    float contrib = 0.f;
    bool act = (l < 25) || (l >= 32 && l < 57);
    if (act) {
        int sel = (l >= 32) ? 1 : 0;
        int p = l - 32 * sel;
        int e = sidx[sel];
        int u = e * 25 + p;
        float2 cs = *(const float2*)(cs_tab + (size_t)q1 * DIM + 2 * u);
        float2 rl = *(const float2*)(rel + (size_t)q1 * REL_DIM + e * 100 + 2 * p);
        float2 rh = *(const float2*)(entity + (size_t)t2 * DIM + 2 * u);
        float2 x  = xs2[u];
        float o0 = cs.x * x.x - cs.y * x.y + rl.x;
        float o1 = cs.y * x.x + cs.x * x.y + rl.y;
        float d0 = o0 - rh.x, d1 = o1 - rh.y;
        contrib = fmaf(d0, d0, d1 * d1);
    }

    // ---- epilogue: gates/probs (row-major ws) while Givens loads are in flight ----
    if (l < NE) {
        float g = (l == sidx[0]) ? sg[0] : ((l == sidx[1]) ? sg[1] : 0.f);
        ws_rows[(size_t)b * 18 + l] = g;
    } else if (l < 18) {
        int e = l - 9;
        float thr_in = sthr[0], thr_out = sthr[1];
        float n = noisy_s[e];
        float thr = (n > thr_in) ? thr_in : thr_out;
        ws_rows[(size_t)b * 18 + 9 + e] = phif((clean_s[e] - thr) / stdv_s[e]);
    }

    // reduce contrib within each 32-lane half (xor stays inside the half)
#pragma unroll
    for (int off = 16; off; off >>= 1) contrib += __shfl_xor(contrib, off);
    float d2b = __shfl(contrib, 32);
    if (l == 0) {
        float c = c_soft[q1];
        float base = bh[q0] + bt[t2];
        float s = expf(base - c * contrib) + expf(base - c * d2b);
        y_out[b] = logf((s == 0.f) ? EPSV : s);
    }
}

// 256 blocks x 64 threads; each thread accumulates 2 rows' 18 values in regs.
// Last finished block performs the final 256-partial reduction + cv^2 loss.
__global__ __launch_bounds__(64) void k_reduce(const float* __restrict__ ws_rows,
                                               float* __restrict__ partials,
                                               int* __restrict__ counter,
                                               float* __restrict__ out)
{
    const int blk = blockIdx.x, t = threadIdx.x;
    float acc[18];
#pragma unroll
    for (int j = 0; j < 18; ++j) acc[j] = 0.f;
    const int r0 = blk * 128 + t * 2;
#pragma unroll
    for (int rr = 0; rr < 2; ++rr) {
        const float2* row = (const float2*)(ws_rows + (size_t)(r0 + rr) * 18);
#pragma unroll
        for (int j = 0; j < 9; ++j) {
            float2 v = row[j];
            acc[2 * j] += v.x; acc[2 * j + 1] += v.y;
        }
    }
#pragma unroll
    for (int j = 0; j < 18; ++j) {
        float v = acc[j];
        for (int off = 32; off; off >>= 1) v += __shfl_down(v, off);
        if (t == 0) partials[blk * 18 + j] = v;
    }

    // last-block-done: device-scope release/acquire around the counter
    __shared__ int is_last;
    __threadfence();
    if (t == 0) {
        int old = atomicAdd(counter, 1);
        is_last = (old == 255) ? 1 : 0;
    }
    __syncthreads();
    if (!is_last) return;
    __threadfence();

    __shared__ float sums[18];
    if (t < 18) {
        float s = 0.f;
        for (int p = 0; p < 256; ++p) s += partials[p * 18 + t];
        sums[t] = s;
    }
    __syncthreads();
    if (t == 0) {
        float loss = 0.f;
#pragma unroll
        for (int part = 0; part < 2; ++part) {
            const float* v = sums + part * NE;
            float mean = 0.f;
            for (int i = 0; i < NE; ++i) mean += v[i];
            mean /= 9.f;
            float var = 0.f;
            for (int i = 0; i < NE; ++i) { float d = v[i] - mean; var += d * d; }
            var /= 8.f;                   // ddof=1
            loss += var / (mean * mean + 1e-10f);
        }
        out[BATCH] = 0.01f * loss;
    }
}

extern "C" void kernel_launch(void* const* d_in, const int* in_sizes, int n_in,
                              void* d_out, int out_size, void* d_ws, size_t ws_size,
                              hipStream_t stream)
{
    const int*   queries = (const int*)d_in[0];
    const int*   these   = (const int*)d_in[1];
    const float* entity  = (const float*)d_in[2];
    const float* rel     = (const float*)d_in[3];
    const float* rel_dg  = (const float*)d_in[4];
    const float* bh      = (const float*)d_in[5];
    const float* bt      = (const float*)d_in[6];
    const float* c_par   = (const float*)d_in[7];
    const float* cnn_w   = (const float*)d_in[8];
    const float* cnn_b   = (const float*)d_in[9];
    const float* h2e_w   = (const float*)d_in[10];
    const float* h2e_b   = (const float*)d_in[11];
    const float* cnnn_w  = (const float*)d_in[12];
    const float* cnnn_b  = (const float*)d_in[13];
    const float* h2en_w  = (const float*)d_in[14];
    const float* h2en_b  = (const float*)d_in[15];
    const float* noise   = (const float*)d_in[16];

    float* y  = (float*)d_out;
    float* ws = (float*)d_ws;
    float* ws_rows  = ws;                                     // BATCH*18
    float* partials = ws + (size_t)BATCH * 18;                // 256*18
    float* cs_tab   = partials + 256 * 18;                    // 22*450
    float* pre_out  = cs_tab + N_REL * DIM;                   // 22*18
    float* c_soft   = pre_out + N_REL * 18;                   // 22
    int*   counter  = (int*)(c_soft + N_REL);                 // 1

    k_pre<<<N_REL, 64, 0, stream>>>(rel, rel_dg, c_par, cnn_w, cnn_b, cnnn_w, cnnn_b,
                                    h2e_w, h2en_w, cs_tab, pre_out, c_soft, counter);
    k_main<<<BATCH, 64, 0, stream>>>(queries, these, entity, rel, bh, bt,
                                     cnn_w, cnn_b, h2e_w, h2e_b, cnnn_w, cnnn_b,
                                     h2en_w, h2en_b, noise, cs_tab, pre_out, c_soft,
                                     y, ws_rows);
    k_reduce<<<256, 64, 0, stream>>>(ws_rows, partials, counter, y);
}

// Round 7
// 192.347 us; speedup vs baseline: 1.8570x; 1.0200x over previous
//
#include <hip/hip_runtime.h>
#include <math.h>

#define BATCH 32768
#define NE 9
#define RANK 50
#define DIM 450            // NE * RANK
#define REL_DIM 900        // 2 * DIM
#define N_REL 22
#define EPSV 2.2204460492503131e-16f

__device__ __forceinline__ float softplusf(float x) {
    return (x > 20.f) ? x : log1pf(expf(x));
}
__device__ __forceinline__ float phif(float z) {
    return 0.5f * (1.f + erff(z * 0.70710678118654752f));
}

// Per-relation precompute: pure-rel conv outputs' dot contributions (o in [48,128)),
// Givens cos/sin table, softplus(c), zero the reduce counter. 22 blocks.
__global__ __launch_bounds__(64) void k_pre(
    const float* __restrict__ rel, const float* __restrict__ rel_diag,
    const float* __restrict__ c_param,
    const float* __restrict__ cnn_w, const float* __restrict__ cnn_b,
    const float* __restrict__ cnnn_w, const float* __restrict__ cnnn_b,
    const float* __restrict__ h2e_w, const float* __restrict__ h2en_w,
    float* __restrict__ cs_tab, float* __restrict__ pre_out, float* __restrict__ c_soft,
    int* __restrict__ counter)
{
    const int r = blockIdx.x;
    const int l = threadIdx.x;
    __shared__ float rl[REL_DIM];
    __shared__ float fA[80], fB[80];

    const float* relp = rel + (size_t)r * REL_DIM;
    for (int i = l; i < REL_DIM; i += 64) rl[i] = relp[i];
    __syncthreads();

    const float cb0 = cnn_b[0], cb1 = cnnn_b[0];
    for (int idx = l; idx < 80; idx += 64) {
        int o = 48 + idx;
        int oh = o >> 4, ow = o & 15;
        const float* base = rl + (oh * 3 - 9) * RANK + ow * 3;   // rel image rows
        float a0 = cb0, a1 = cb1;
#pragma unroll
        for (int i = 0; i < 5; ++i)
#pragma unroll
            for (int j = 0; j < 5; ++j) {
                float v = base[i * RANK + j];
                a0 = fmaf(v, cnn_w[i * 5 + j], a0);
                a1 = fmaf(v, cnnn_w[i * 5 + j], a1);
            }
        fA[idx] = a0; fB[idx] = a1;
    }
    __syncthreads();

    if (l < 18) {
        int e = (l < 9) ? l : (l - 9);
        const float* w = ((l < 9) ? (h2e_w + e * 128) : (h2en_w + e * 128)) + 48;
        const float* f = (l < 9) ? fA : fB;
        float acc = 0.f;
#pragma unroll 8
        for (int t = 0; t < 80; ++t) acc = fmaf(f[t], w[t], acc);
        pre_out[r * 18 + l] = acc;
    }
    if (l == 63) c_soft[r] = softplusf(c_param[r]);
    if (r == 0 && l == 62) *counter = 0;        // zero last-block counter each launch

    const float2* rd2 = (const float2*)(rel_diag + (size_t)r * DIM);
    float2* cs2 = (float2*)(cs_tab + (size_t)r * DIM);
    for (int u = l; u < 225; u += 64) {
        float2 v = rd2[u];
        float nrm = fmaxf(sqrtf(v.x * v.x + v.y * v.y), 1e-15f);
        cs2[u] = make_float2(v.x / nrm, v.y / nrm);
    }
}

// One 64-lane wave per sample; 2 barriers; rhs row prefetched; top-k in registers.
__global__ __launch_bounds__(64) void k_main(
    const int* __restrict__ queries, const int* __restrict__ these_queries,
    const float* __restrict__ entity, const float* __restrict__ rel,
    const float* __restrict__ bh, const float* __restrict__ bt,
    const float* __restrict__ cnn_w, const float* __restrict__ cnn_b,
    const float* __restrict__ h2e_w, const float* __restrict__ h2e_b,
    const float* __restrict__ cnnn_w, const float* __restrict__ cnnn_b,
    const float* __restrict__ h2en_w, const float* __restrict__ h2en_b,
    const float* __restrict__ noise,
    const float* __restrict__ cs_tab, const float* __restrict__ pre_out,
    const float* __restrict__ c_soft,
    float* __restrict__ y_out, float* __restrict__ ws_rows)
{
    const int b = blockIdx.x;
    const int l = threadIdx.x;

    __shared__ __align__(16) float xs[1000];    // [0:450) head, [450:550) rel[0:100), [550:1000) rhs row
    __shared__ __align__(8) float2 fs[51];      // (feat, featn) per o<48, padded 1/16

    const int q0 = queries[b * 3 + 0];
    const int q1 = queries[b * 3 + 1];
    const int t2 = these_queries[b * 3 + 2];

    const float2* hp2 = (const float2*)(entity + (size_t)q0 * DIM);   // 225 float2
    const float2* rp2 = (const float2*)(rel + (size_t)q1 * REL_DIM);  // first 50
    const float2* tp2 = (const float2*)(entity + (size_t)t2 * DIM);   // 225 float2

    // ---- issue ALL sample-dependent row loads at wave start ----
    float2 h2[4], tv[4];
#pragma unroll
    for (int k = 0; k < 4; ++k) { int i = l + 64 * k; if (i < 225) { h2[k] = hp2[i]; tv[k] = tp2[i]; } }
    float2 rr2 = make_float2(0.f, 0.f);
    if (l < 50) rr2 = rp2[l];
    float nz = (l < NE) ? noise[(size_t)b * NE + l] : 0.f;
    float pre_v = (l < 18) ? pre_out[q1 * 18 + l] : 0.f;
    const float bhv = bh[q0], btv = bt[t2], cso = c_soft[q1];

    float2* xs2 = (float2*)xs;
#pragma unroll
    for (int k = 0; k < 4; ++k) { int i = l + 64 * k; if (i < 225) { xs2[i] = h2[k]; xs2[275 + i] = tv[k]; } }
    if (l < 50) xs2[225 + l] = rr2;
    __syncthreads();

    // ---- conv: sample-dependent outputs o < 48 (oh 0..2), both kernels ----
    if (l < 48) {
        int oh = l >> 4, ow = l & 15;
        const float* base = xs + (oh * 3) * RANK + ow * 3;
        float a0 = cnn_b[0], a1 = cnnn_b[0];
#pragma unroll
        for (int i = 0; i < 5; ++i)
#pragma unroll
            for (int j = 0; j < 5; ++j) {
                float v = base[i * RANK + j];
                a0 = fmaf(v, cnn_w[i * 5 + j], a0);
                a1 = fmaf(v, cnnn_w[i * 5 + j], a1);
            }
        fs[l + (l >> 4)] = make_float2(a0, a1);
    }
    __syncthreads();

    // ---- 18 dots of length 48: 54 lanes, 16 terms each ----
    float acc = 0.f;
    if (l < 54) {
        int chunk = l / 18, j = l - chunk * 18;
        int e = (j < 9) ? j : (j - 9);
        const float* wrow = ((j < 9) ? (h2e_w + e * 128) : (h2en_w + e * 128)) + chunk * 16;
        int fbase = chunk * 17;   // padded chunk base
        if (j < 9) {
#pragma unroll
            for (int k = 0; k < 16; ++k) acc = fmaf(fs[fbase + k].x, wrow[k], acc);
        } else {
#pragma unroll
            for (int k = 0; k < 16; ++k) acc = fmaf(fs[fbase + k].y, wrow[k], acc);
        }
    }
    float pA = __shfl_down(acc, 18);
    float pB = __shfl_down(acc, 36);
    float tot = acc + pA + pB;                  // valid for l < 18

    // ---- clean / stdv / noisy in registers (no LDS, no barrier) ----
    float clean_r = 0.f, stdv_r = 0.f;
    if (l < 9)        clean_r = tot + pre_v + h2e_b[l];
    else if (l < 18)  stdv_r  = softplusf(tot + pre_v + h2en_b[l - 9]) + 0.01f;
    float stdv_me = __shfl(stdv_r, (l < 9) ? (l + 9) : 0);   // lanes 0-8: their sigma
    float noisy_r = (l < 9) ? fmaf(nz, stdv_me, clean_r) : 0.f;

    // ---- top-3 of 9 on ALL lanes via shuffle broadcast (ties -> lower index) ----
    int i0 = -1, i1 = -1;
    float v0 = -__builtin_huge_valf(), v1 = v0, v2 = v0;
#pragma unroll
    for (int e = 0; e < NE; ++e) {
        float v = __shfl(noisy_r, e);
        if (v > v0)      { v2 = v1; v1 = v0; i1 = i0; v0 = v; i0 = e; }
        else if (v > v1) { v2 = v1; v1 = v; i1 = e; }
        else if (v > v2) { v2 = v; }
    }
    float e1g = __expf(v1 - v0);
    float invg = 1.f / (1.f + e1g);
    float g0 = invg, g1 = e1g * invg;

    // converged shuffles for the prob lanes (9..17)
    int esrc = (l >= 9 && l < 18) ? (l - 9) : 0;
    float clean_e = __shfl(clean_r, esrc);
    float noisy_e = __shfl(noisy_r, esrc);

    // ---- Givens + dist2 for the 2 selected experts; rhs from LDS ----
    float contrib = 0.f;
    bool act = (l < 25) || (l >= 32 && l < 57);
    if (act) {
        int sel = (l >= 32) ? 1 : 0;
        int p = l - 32 * sel;
        int e = sel ? i1 : i0;
        int u = e * 25 + p;
        float2 cs = *(const float2*)(cs_tab + (size_t)q1 * DIM + 2 * u);
        float2 rl = *(const float2*)(rel + (size_t)q1 * REL_DIM + e * 100 + 2 * p);
        float2 rh = xs2[275 + u];
        float2 x  = xs2[u];
        float o0 = cs.x * x.x - cs.y * x.y + rl.x;
        float o1 = cs.y * x.x + cs.x * x.y + rl.y;
        float d0 = o0 - rh.x, d1 = o1 - rh.y;
        contrib = fmaf(d0, d0, d1 * d1);
    }

    // ---- epilogue: gates/probs (row-major ws) while cs/rl loads are in flight ----
    if (l < NE) {
        float g = (l == i0) ? g0 : ((l == i1) ? g1 : 0.f);
        ws_rows[(size_t)b * 18 + l] = g;
    } else if (l < 18) {
        float thr = (noisy_e > v2) ? v2 : v1;
        ws_rows[(size_t)b * 18 + l] = phif((clean_e - thr) / stdv_r);
    }

    // reduce contrib within each 32-lane half (xor stays inside the half)
#pragma unroll
    for (int off = 16; off; off >>= 1) contrib += __shfl_xor(contrib, off);
    float d2b = __shfl(contrib, 32);
    if (l == 0) {
        float base = bhv + btv;
        float s = __expf(base - cso * contrib) + __expf(base - cso * d2b);
        y_out[b] = __logf((s == 0.f) ? EPSV : s);
    }
}

// 256 blocks x 64 threads; each thread accumulates 2 rows' 18 values in regs.
// Last finished block performs the final 256-partial reduction + cv^2 loss.
__global__ __launch_bounds__(64) void k_reduce(const float* __restrict__ ws_rows,
                                               float* __restrict__ partials,
                                               int* __restrict__ counter,
                                               float* __restrict__ out)
{
    const int blk = blockIdx.x, t = threadIdx.x;
    float acc[18];
#pragma unroll
    for (int j = 0; j < 18; ++j) acc[j] = 0.f;
    const int r0 = blk * 128 + t * 2;
#pragma unroll
    for (int rr = 0; rr < 2; ++rr) {
        const float2* row = (const float2*)(ws_rows + (size_t)(r0 + rr) * 18);
#pragma unroll
        for (int j = 0; j < 9; ++j) {
            float2 v = row[j];
            acc[2 * j] += v.x; acc[2 * j + 1] += v.y;
        }
    }
#pragma unroll
    for (int j = 0; j < 18; ++j) {
        float v = acc[j];
        for (int off = 32; off; off >>= 1) v += __shfl_down(v, off);
        if (t == 0) partials[blk * 18 + j] = v;
    }

    // last-block-done: device-scope release/acquire around the counter
    __shared__ int is_last;
    __threadfence();
    if (t == 0) {
        int old = atomicAdd(counter, 1);
        is_last = (old == 255) ? 1 : 0;
    }
    __syncthreads();
    if (!is_last) return;
    __threadfence();

    __shared__ float sums[18];
    if (t < 18) {
        float s = 0.f;
        for (int p = 0; p < 256; ++p) s += partials[p * 18 + t];
        sums[t] = s;
    }
    __syncthreads();
    if (t == 0) {
        float loss = 0.f;
#pragma unroll
        for (int part = 0; part < 2; ++part) {
            const float* v = sums + part * NE;
            float mean = 0.f;
            for (int i = 0; i < NE; ++i) mean += v[i];
            mean /= 9.f;
            float var = 0.f;
            for (int i = 0; i < NE; ++i) { float d = v[i] - mean; var += d * d; }
            var /= 8.f;                   // ddof=1
            loss += var / (mean * mean + 1e-10f);
        }
        out[BATCH] = 0.01f * loss;
    }
}

extern "C" void kernel_launch(void* const* d_in, const int* in_sizes, int n_in,
                              void* d_out, int out_size, void* d_ws, size_t ws_size,
                              hipStream_t stream)
{
    const int*   queries = (const int*)d_in[0];
    const int*   these   = (const int*)d_in[1];
    const float* entity  = (const float*)d_in[2];
    const float* rel     = (const float*)d_in[3];
    const float* rel_dg  = (const float*)d_in[4];
    const float* bh      = (const float*)d_in[5];
    const float* bt      = (const float*)d_in[6];
    const float* c_par   = (const float*)d_in[7];
    const float* cnn_w   = (const float*)d_in[8];
    const float* cnn_b   = (const float*)d_in[9];
    const float* h2e_w   = (const float*)d_in[10];
    const float* h2e_b   = (const float*)d_in[11];
    const float* cnnn_w  = (const float*)d_in[12];
    const float* cnnn_b  = (const float*)d_in[13];
    const float* h2en_w  = (const float*)d_in[14];
    const float* h2en_b  = (const float*)d_in[15];
    const float* noise   = (const float*)d_in[16];

    float* y  = (float*)d_out;
    float* ws = (float*)d_ws;
    float* ws_rows  = ws;                                     // BATCH*18
    float* partials = ws + (size_t)BATCH * 18;                // 256*18
    float* cs_tab   = partials + 256 * 18;                    // 22*450
    float* pre_out  = cs_tab + N_REL * DIM;                   // 22*18
    float* c_soft   = pre_out + N_REL * 18;                   // 22
    int*   counter  = (int*)(c_soft + N_REL);                 // 1

    k_pre<<<N_REL, 64, 0, stream>>>(rel, rel_dg, c_par, cnn_w, cnn_b, cnnn_w, cnnn_b,
                                    h2e_w, h2en_w, cs_tab, pre_out, c_soft, counter);
    k_main<<<BATCH, 64, 0, stream>>>(queries, these, entity, rel, bh, bt,
                                     cnn_w, cnn_b, h2e_w, h2e_b, cnnn_w, cnnn_b,
                                     h2en_w, h2en_b, noise, cs_tab, pre_out, c_soft,
                                     y, ws_rows);
    k_reduce<<<256, 64, 0, stream>>>(ws_rows, partials, counter, y);
}